// Round 4
// baseline (439.568 us; speedup 1.0000x reference)
//
#include <hip/hip_runtime.h>
#include <hip/hip_bf16.h>
#include <stdint.h>

#define N_NODES 100000
#define F_IN    512
#define HOUT    16

#define BSH   9                       // 512 nodes per bucket
#define NBUK  196                     // ceil(100000 / 512)
#define CAP   18432                   // per-bucket capacity (mean 16327, +16 sigma)
#define CHUNK 4096                    // edges per k_binA block

typedef __attribute__((ext_vector_type(8))) short bf16x8;
typedef __attribute__((ext_vector_type(4))) float f32x4;

// f32 -> bf16 bits, round-to-nearest-even
__device__ __forceinline__ short f2bf(float f) {
    union { float f; uint32_t u; } v; v.f = f;
    uint32_t r = (v.u + 0x7FFFu + ((v.u >> 16) & 1u)) >> 16;
    return (short)r;
}
__device__ __forceinline__ float bf2f(uint32_t bits16) {
    union { uint32_t u; float f; } v; v.u = bits16 << 16;
    return v.f;
}

// ---- K0: detect edge_index dtype (int64 vs int32) ----------------------
__global__ void k_detect(const uint32_t* __restrict__ e_u32, uint32_t* __restrict__ flag) {
    if (blockIdx.x == 0 && threadIdx.x == 0) {
        uint32_t o = 0;
        #pragma unroll
        for (int i = 1; i < 32; i += 2) o |= e_u32[i];
        flag[0] = (o == 0u) ? 1u : 0u; // 1 => int64
    }
}

__device__ __forceinline__ int edge_at(const void* ei, int64_t idx, uint32_t is64) {
    if (is64) return (int)((const long long*)ei)[idx];
    return ((const int*)ei)[idx];
}

// ---- Pass A: bin edges into 196 coarse buckets (LDS-staged, coalesced) --
__global__ __launch_bounds__(256) void k_binA(const void* __restrict__ ei, int E,
                                              const uint32_t* __restrict__ flag,
                                              uint32_t* __restrict__ bucket_woff,
                                              uint32_t* __restrict__ gpairs) {
    const uint32_t is64 = flag[0];
    const int t = threadIdx.x;
    const int base = blockIdx.x * CHUNK;
    const int chunk_n = min(CHUNK, E - base);

    __shared__ uint32_t h[256];
    __shared__ uint32_t ex[257];
    __shared__ uint32_t pcnt[256];
    __shared__ uint32_t gbase[256];
    __shared__ uint32_t sorted[CHUNK];
    __shared__ uint8_t  sbuck[CHUNK];

    h[t] = 0;
    __syncthreads();

    uint32_t pr[16], bk[16];
    #pragma unroll
    for (int k = 0; k < 16; ++k) {
        int e = base + k * 256 + t;
        bk[k] = 0xFFFFFFFFu;
        if (e < E) {
            uint32_t s = (uint32_t)edge_at(ei, e, is64);
            uint32_t d = (uint32_t)edge_at(ei, (int64_t)E + e, is64);
            uint32_t b = d >> BSH;
            pr[k] = (s << BSH) | (d & ((1u << BSH) - 1u));
            bk[k] = b;
            atomicAdd(&h[b], 1u);
        }
    }
    __syncthreads();

    const uint32_t hv = h[t];
    for (int off = 1; off < 256; off <<= 1) {
        uint32_t v = (t >= off) ? h[t - off] : 0u;
        __syncthreads();
        h[t] += v;
        __syncthreads();
    }
    ex[t + 1] = h[t];
    if (t == 0) ex[0] = 0;
    __syncthreads();
    pcnt[t] = ex[t];
    if (t < NBUK) gbase[t] = atomicAdd(&bucket_woff[t], hv);
    __syncthreads();

    #pragma unroll
    for (int k = 0; k < 16; ++k) {
        if (bk[k] != 0xFFFFFFFFu) {
            uint32_t slot = atomicAdd(&pcnt[bk[k]], 1u);
            sorted[slot] = pr[k];
            sbuck[slot] = (uint8_t)bk[k];
        }
    }
    __syncthreads();

    #pragma unroll
    for (int k = 0; k < 16; ++k) {
        int i = k * 256 + t;
        if (i < chunk_n) {
            uint32_t b = sbuck[i];
            uint32_t pos = gbase[b] + ((uint32_t)i - ex[b]);
            gpairs[(size_t)b * CAP + pos] = sorted[i];
        }
    }
}

// ---- per-bucket exact histogram -> cnt ----------------------------------
__global__ __launch_bounds__(256) void k_hist(const uint32_t* __restrict__ bucket_woff,
                                              const uint32_t* __restrict__ gpairs,
                                              uint32_t* __restrict__ cnt) {
    const int b = blockIdx.x;
    const int t = threadIdx.x;
    const uint32_t count = bucket_woff[b];
    const uint32_t* gp = gpairs + (size_t)b * CAP;

    __shared__ uint32_t lc[512];
    lc[t] = 0; lc[t + 256] = 0;
    __syncthreads();
    for (uint32_t i = t; i < count; i += 256)
        atomicAdd(&lc[gp[i] & 511u], 1u);
    __syncthreads();
    #pragma unroll
    for (int j = 0; j < 2; ++j) {
        int dl = t + 256 * j;
        int gn = (b << BSH) + dl;
        if (gn < N_NODES) cnt[gn] = lc[dl];
    }
}

// ---- GEMM: hs = (x @ W) * dinv, bf16 MFMA, bf16 output ------------------
__global__ __launch_bounds__(256) void k_gemm(const float* __restrict__ x,
                                              const float* __restrict__ W,
                                              const uint32_t* __restrict__ cnt,
                                              ushort* __restrict__ hsb) {
    const int lane = threadIdx.x & 63;
    const int wid  = threadIdx.x >> 6;
    const int tile = blockIdx.x * 4 + wid;
    if (tile * 16 >= N_NODES) return;
    const int c    = lane & 15;
    const int half = lane >> 4;

    bf16x8 bfrag[16];
    #pragma unroll
    for (int s = 0; s < 16; ++s) {
        #pragma unroll
        for (int e = 0; e < 8; ++e) {
            int k = 32 * s + 8 * half + e;
            bfrag[s][e] = f2bf(W[k * HOUT + c]);
        }
    }

    const int row = tile * 16 + c;
    const float* xr = x + (int64_t)row * F_IN;
    f32x4 acc = {0.f, 0.f, 0.f, 0.f};
    #pragma unroll
    for (int s = 0; s < 16; ++s) {
        const float4 a0 = *(const float4*)(xr + 32 * s + 8 * half);
        const float4 a1 = *(const float4*)(xr + 32 * s + 8 * half + 4);
        bf16x8 af;
        af[0] = f2bf(a0.x); af[1] = f2bf(a0.y); af[2] = f2bf(a0.z); af[3] = f2bf(a0.w);
        af[4] = f2bf(a1.x); af[5] = f2bf(a1.y); af[6] = f2bf(a1.z); af[7] = f2bf(a1.w);
        acc = __builtin_amdgcn_mfma_f32_16x16x32_bf16(af, bfrag[s], acc, 0, 0, 0);
    }

    #pragma unroll
    for (int r = 0; r < 4; ++r) {
        int orow = tile * 16 + 4 * half + r;
        float dinv = rsqrtf((float)(cnt[orow] + 1u));
        hsb[(int64_t)orow * HOUT + c] = (ushort)f2bf(acc[r] * dinv);
    }
}

// ---- fused per-bucket aggregate + epilogue ------------------------------
// One block per bucket (512 nodes), 1024 threads = 64 edge-groups of 16.
__global__ __launch_bounds__(1024) void k_aggB(const uint32_t* __restrict__ bucket_woff,
                                               const uint32_t* __restrict__ gpairs,
                                               const uint32_t* __restrict__ cnt,
                                               const ushort* __restrict__ hsb,
                                               const float* __restrict__ bias,
                                               float* __restrict__ out) {
    const int bk = blockIdx.x;
    const int t = threadIdx.x;
    const uint32_t count = bucket_woff[bk];
    const uint32_t* gp = gpairs + (size_t)bk * CAP;

    __shared__ float acc[512][17]; // +1 pad: bank = (dl*17 + f) & 31
    float* af = &acc[0][0];
    for (int i = t; i < 512 * 17; i += 1024) af[i] = 0.f;
    __syncthreads();

    const int f = t & 15;
    const uint32_t group = t >> 4; // 0..63

    uint32_t j = group;
    for (; j + 64 < count; j += 128) {
        uint32_t p0 = gp[j];
        uint32_t p1 = gp[j + 64];
        uint32_t h0 = hsb[(size_t)(p0 >> BSH) * HOUT + f];
        uint32_t h1 = hsb[(size_t)(p1 >> BSH) * HOUT + f];
        atomicAdd(&acc[p0 & 511u][f], bf2f(h0));
        atomicAdd(&acc[p1 & 511u][f], bf2f(h1));
    }
    if (j < count) {
        uint32_t p0 = gp[j];
        uint32_t h0 = hsb[(size_t)(p0 >> BSH) * HOUT + f];
        atomicAdd(&acc[p0 & 511u][f], bf2f(h0));
    }
    __syncthreads();

    const float bf = bias[f];
    #pragma unroll
    for (int i = 0; i < 8; ++i) {
        int dl = (int)group + 64 * i;
        int gn = (bk << BSH) + dl;
        if (gn >= N_NODES) break;
        const uint32_t deg = cnt[gn];
        const float dinv = rsqrtf((float)(deg + 1u));
        const float self = bf2f(hsb[(size_t)gn * HOUT + f]);
        float v = fmaxf(fmaf(dinv, acc[dl][f] + self, bf), 0.f);

        float m = v;
        #pragma unroll
        for (int d = 1; d < 16; d <<= 1) m = fmaxf(m, __shfl_xor(m, d));
        float ex = __expf(v - m);
        float sum = ex;
        #pragma unroll
        for (int d = 1; d < 16; d <<= 1) sum += __shfl_xor(sum, d);
        out[(size_t)gn * HOUT + f] = v - (m + __logf(sum));
    }
}

extern "C" void kernel_launch(void* const* d_in, const int* in_sizes, int n_in,
                              void* d_out, int out_size, void* d_ws, size_t ws_size,
                              hipStream_t stream) {
    const float* x  = (const float*)d_in[0];
    const void*  ei = d_in[1];
    const float* W  = (const float*)d_in[2];
    const float* b  = (const float*)d_in[3];
    float* out = (float*)d_out;
    const int E = in_sizes[1] / 2;

    char* ws = (char*)d_ws;
    uint32_t* flag        = (uint32_t*)ws;                  // 4 B
    uint32_t* bucket_woff = (uint32_t*)(ws + 1024);         // 784 B
    uint32_t* gpairs      = (uint32_t*)(ws + (1 << 20));    // 14.45 MB
    ushort*   hsb         = (ushort*)(ws + (16 << 20));     // 3.2 MB
    uint32_t* cnt         = (uint32_t*)(ws + (20 << 20));   // 400 KB

    hipMemsetAsync(bucket_woff, 0, NBUK * sizeof(uint32_t), stream);

    k_detect<<<1, 64, 0, stream>>>((const uint32_t*)ei, flag);
    k_binA<<<(E + CHUNK - 1) / CHUNK, 256, 0, stream>>>(ei, E, flag, bucket_woff, gpairs);
    k_hist<<<NBUK, 256, 0, stream>>>(bucket_woff, gpairs, cnt);
    k_gemm<<<(6250 + 3) / 4, 256, 0, stream>>>(x, W, cnt, hsb);
    k_aggB<<<NBUK, 1024, 0, stream>>>(bucket_woff, gpairs, cnt, hsb, b, out);
}

// Round 5
// 120.065 us; speedup vs baseline: 3.6611x; 3.6611x over previous
//
#include <hip/hip_runtime.h>
#include <hip/hip_bf16.h>
#include <stdint.h>

#define N_NODES 100000
#define F_IN    512
#define HOUT    16

#define BSH   8                       // 256 nodes per bucket
#define NBUK  391                     // ceil(100000 / 256)
#define CAP   9216                    // per-bucket capacity (mean 8184, +11 sigma)
#define CHUNK 8192                    // edges per k_binA block

typedef __attribute__((ext_vector_type(8))) short bf16x8;
typedef __attribute__((ext_vector_type(4))) float f32x4;

// f32 -> bf16 bits, round-to-nearest-even
__device__ __forceinline__ short f2bf(float f) {
    union { float f; uint32_t u; } v; v.f = f;
    uint32_t r = (v.u + 0x7FFFu + ((v.u >> 16) & 1u)) >> 16;
    return (short)r;
}
__device__ __forceinline__ float bf2f(uint32_t bits16) {
    union { uint32_t u; float f; } v; v.u = bits16 << 16;
    return v.f;
}

// ---- K0: detect edge_index dtype (int64 vs int32) ----------------------
__global__ void k_detect(const uint32_t* __restrict__ e_u32, uint32_t* __restrict__ flag) {
    if (blockIdx.x == 0 && threadIdx.x == 0) {
        uint32_t o = 0;
        #pragma unroll
        for (int i = 1; i < 32; i += 2) o |= e_u32[i];
        flag[0] = (o == 0u) ? 1u : 0u; // 1 => int64
    }
}

__device__ __forceinline__ int edge_at(const void* ei, int64_t idx, uint32_t is64) {
    if (is64) return (int)((const long long*)ei)[idx];
    return ((const int*)ei)[idx];
}

// ---- Pass A: bin edges into 391 buckets (LDS counting sort, coalesced out)
__global__ __launch_bounds__(512) void k_binA(const void* __restrict__ ei, int E,
                                              const uint32_t* __restrict__ flag,
                                              uint32_t* __restrict__ bucket_woff,
                                              uint32_t* __restrict__ gpairs) {
    const uint32_t is64 = flag[0];
    const int t = threadIdx.x;
    const int base = blockIdx.x * CHUNK;
    const int chunk_n = min(CHUNK, E - base);

    __shared__ uint32_t h[512];        // histogram -> inclusive scan in place
    __shared__ uint32_t ex[512];       // exclusive scan (frozen)
    __shared__ uint32_t pcnt[512];     // placement cursors
    __shared__ uint32_t gbase[512];    // global reservation per bucket
    __shared__ uint32_t sorted[CHUNK]; // bucket-sorted packed pairs (32 KB)
    __shared__ uint16_t sbuck[CHUNK];  // bucket id per slot (16 KB)

    h[t] = 0;
    __syncthreads();

    uint32_t pr[16];
    uint16_t bk[16];
    #pragma unroll
    for (int k = 0; k < 16; ++k) {
        int e = base + k * 512 + t;
        bk[k] = 0xFFFFu;
        if (e < E) {
            uint32_t s = (uint32_t)edge_at(ei, e, is64);
            uint32_t d = (uint32_t)edge_at(ei, (int64_t)E + e, is64);
            uint32_t b = d >> BSH;
            pr[k] = (s << BSH) | (d & ((1u << BSH) - 1u));
            bk[k] = (uint16_t)b;
            atomicAdd(&h[b], 1u);
        }
    }
    __syncthreads();

    const uint32_t hv = h[t];
    // Hillis-Steele inclusive scan over 512 bins
    for (int off = 1; off < 512; off <<= 1) {
        uint32_t v = (t >= off) ? h[t - off] : 0u;
        __syncthreads();
        h[t] += v;
        __syncthreads();
    }
    ex[t] = h[t] - hv;
    pcnt[t] = ex[t];
    if (t < NBUK) gbase[t] = atomicAdd(&bucket_woff[t], hv);
    __syncthreads();

    #pragma unroll
    for (int k = 0; k < 16; ++k) {
        if (bk[k] != 0xFFFFu) {
            uint32_t slot = atomicAdd(&pcnt[bk[k]], 1u);
            sorted[slot] = pr[k];
            sbuck[slot] = bk[k];
        }
    }
    __syncthreads();

    #pragma unroll
    for (int k = 0; k < 16; ++k) {
        int i = k * 512 + t;
        if (i < chunk_n) {
            uint32_t b = sbuck[i];
            uint32_t pos = gbase[b] + ((uint32_t)i - ex[b]);
            gpairs[(size_t)b * CAP + pos] = sorted[i];
        }
    }
}

// ---- per-bucket exact histogram -> cnt ----------------------------------
__global__ __launch_bounds__(256) void k_hist(const uint32_t* __restrict__ bucket_woff,
                                              const uint32_t* __restrict__ gpairs,
                                              uint32_t* __restrict__ cnt) {
    const int b = blockIdx.x;
    const int t = threadIdx.x;
    const uint32_t count = bucket_woff[b];
    const uint32_t* gp = gpairs + (size_t)b * CAP;

    __shared__ uint32_t lc[256];
    lc[t] = 0;
    __syncthreads();
    for (uint32_t i = t; i < count; i += 256)
        atomicAdd(&lc[gp[i] & 255u], 1u);
    __syncthreads();
    int gn = (b << BSH) + t;
    if (gn < N_NODES) cnt[gn] = lc[t];
}

// ---- GEMM: hs = (x @ W) * dinv, bf16 MFMA, bf16 output ------------------
__global__ __launch_bounds__(256) void k_gemm(const float* __restrict__ x,
                                              const float* __restrict__ W,
                                              const uint32_t* __restrict__ cnt,
                                              ushort* __restrict__ hsb) {
    const int lane = threadIdx.x & 63;
    const int wid  = threadIdx.x >> 6;
    const int tile = blockIdx.x * 4 + wid;
    if (tile * 16 >= N_NODES) return;
    const int c    = lane & 15;
    const int half = lane >> 4;

    bf16x8 bfrag[16];
    #pragma unroll
    for (int s = 0; s < 16; ++s) {
        #pragma unroll
        for (int e = 0; e < 8; ++e) {
            int k = 32 * s + 8 * half + e;
            bfrag[s][e] = f2bf(W[k * HOUT + c]);
        }
    }

    const int row = tile * 16 + c;
    const float* xr = x + (int64_t)row * F_IN;
    f32x4 acc = {0.f, 0.f, 0.f, 0.f};
    #pragma unroll
    for (int s = 0; s < 16; ++s) {
        const float4 a0 = *(const float4*)(xr + 32 * s + 8 * half);
        const float4 a1 = *(const float4*)(xr + 32 * s + 8 * half + 4);
        bf16x8 af;
        af[0] = f2bf(a0.x); af[1] = f2bf(a0.y); af[2] = f2bf(a0.z); af[3] = f2bf(a0.w);
        af[4] = f2bf(a1.x); af[5] = f2bf(a1.y); af[6] = f2bf(a1.z); af[7] = f2bf(a1.w);
        acc = __builtin_amdgcn_mfma_f32_16x16x32_bf16(af, bfrag[s], acc, 0, 0, 0);
    }

    #pragma unroll
    for (int r = 0; r < 4; ++r) {
        int orow = tile * 16 + 4 * half + r;
        float dinv = rsqrtf((float)(cnt[orow] + 1u));
        hsb[(int64_t)orow * HOUT + c] = (ushort)f2bf(acc[r] * dinv);
    }
}

// ---- fused per-bucket sort(to LDS) + gather-aggregate + epilogue --------
// One block per bucket (256 nodes), 512 threads.
__global__ __launch_bounds__(512) void k_sortagg(const uint32_t* __restrict__ bucket_woff,
                                                 const uint32_t* __restrict__ gpairs,
                                                 const uint32_t* __restrict__ cnt,
                                                 const ushort* __restrict__ hsb,
                                                 const float* __restrict__ bias,
                                                 float* __restrict__ out) {
    const int bk = blockIdx.x;
    const int t = threadIdx.x;
    const uint32_t count = bucket_woff[bk];
    const uint32_t* gp = gpairs + (size_t)bk * CAP;

    __shared__ uint32_t lc[256];   // per-node degree
    __shared__ uint32_t st[256];   // run start (frozen)
    __shared__ uint32_t cur[256];  // placement cursor
    __shared__ uint32_t sc[256];   // scan scratch
    __shared__ uint32_t lsrc[CAP]; // srcs sorted by dst-local (36 KB)

    if (t < 256) {
        int gn = (bk << BSH) + t;
        lc[t] = (gn < N_NODES) ? cnt[gn] : 0u;
        sc[t] = lc[t];
    }
    __syncthreads();
    for (int off = 1; off < 256; off <<= 1) {
        uint32_t v = 0;
        if (t < 256 && t >= off) v = sc[t - off];
        __syncthreads();
        if (t < 256) sc[t] += v;
        __syncthreads();
    }
    if (t < 256) {
        st[t] = sc[t] - lc[t];
        cur[t] = st[t];
    }
    __syncthreads();

    for (uint32_t i = t; i < count; i += 512) {
        uint32_t p = gp[i];
        uint32_t pos = atomicAdd(&cur[p & 255u], 1u);
        lsrc[pos] = p >> BSH;
    }
    __syncthreads();

    const int f = t & 15;
    const int g = t >> 4; // 0..31
    const float bf = bias[f];

    #pragma unroll
    for (int i = 0; i < 8; ++i) {
        int dl = g + 32 * i;
        int gn = (bk << BSH) + dl;
        if (gn >= N_NODES) break;
        const uint32_t s0 = st[dl];
        const uint32_t n  = lc[dl];

        float acc = 0.f;
        uint32_t j = 0;
        for (; j + 4 <= n; j += 4) {
            uint32_t a = lsrc[s0 + j], b2 = lsrc[s0 + j + 1];
            uint32_t c2 = lsrc[s0 + j + 2], d2 = lsrc[s0 + j + 3];
            float v0 = bf2f(hsb[(size_t)a  * HOUT + f]);
            float v1 = bf2f(hsb[(size_t)b2 * HOUT + f]);
            float v2 = bf2f(hsb[(size_t)c2 * HOUT + f]);
            float v3 = bf2f(hsb[(size_t)d2 * HOUT + f]);
            acc += (v0 + v1) + (v2 + v3);
        }
        for (; j < n; ++j)
            acc += bf2f(hsb[(size_t)lsrc[s0 + j] * HOUT + f]);

        const float dinv = rsqrtf((float)(n + 1u));
        const float self = bf2f(hsb[(size_t)gn * HOUT + f]);
        float v = fmaxf(fmaf(dinv, acc + self, bf), 0.f);

        float m = v;
        #pragma unroll
        for (int d = 1; d < 16; d <<= 1) m = fmaxf(m, __shfl_xor(m, d));
        float ex = __expf(v - m);
        float sum = ex;
        #pragma unroll
        for (int d = 1; d < 16; d <<= 1) sum += __shfl_xor(sum, d);
        out[(size_t)gn * HOUT + f] = v - (m + __logf(sum));
    }
}

extern "C" void kernel_launch(void* const* d_in, const int* in_sizes, int n_in,
                              void* d_out, int out_size, void* d_ws, size_t ws_size,
                              hipStream_t stream) {
    const float* x  = (const float*)d_in[0];
    const void*  ei = d_in[1];
    const float* W  = (const float*)d_in[2];
    const float* b  = (const float*)d_in[3];
    float* out = (float*)d_out;
    const int E = in_sizes[1] / 2;

    char* ws = (char*)d_ws;
    uint32_t* flag        = (uint32_t*)ws;                  // 4 B
    uint32_t* bucket_woff = (uint32_t*)(ws + 1024);         // 1.6 KB
    uint32_t* gpairs      = (uint32_t*)(ws + (1 << 20));    // 14.42 MB
    ushort*   hsb         = (ushort*)(ws + (16 << 20));     // 3.2 MB
    uint32_t* cnt         = (uint32_t*)(ws + (20 << 20));   // 400 KB

    hipMemsetAsync(bucket_woff, 0, NBUK * sizeof(uint32_t), stream);

    k_detect<<<1, 64, 0, stream>>>((const uint32_t*)ei, flag);
    k_binA<<<(E + CHUNK - 1) / CHUNK, 512, 0, stream>>>(ei, E, flag, bucket_woff, gpairs);
    k_hist<<<NBUK, 256, 0, stream>>>(bucket_woff, gpairs, cnt);
    k_gemm<<<(6250 + 3) / 4, 256, 0, stream>>>(x, W, cnt, hsb);
    k_sortagg<<<NBUK, 512, 0, stream>>>(bucket_woff, gpairs, cnt, hsb, b, out);
}

// Round 6
// 112.165 us; speedup vs baseline: 3.9189x; 1.0704x over previous
//
#include <hip/hip_runtime.h>
#include <hip/hip_bf16.h>
#include <stdint.h>

#define N_NODES 100000
#define F_IN    512
#define HOUT    16

#define BSH   8                       // 256 nodes per bucket
#define NBUK  391                     // ceil(100000 / 256)
#define CAP   9216                    // per-bucket capacity (mean 8184, +11 sigma)
#define CHUNK 8192                    // edges per binA block
#define GEMM_BLOCKS 782               // ceil(6250 tiles / 8 waves)

typedef __attribute__((ext_vector_type(8))) short bf16x8;
typedef __attribute__((ext_vector_type(4))) float f32x4;

// f32 -> bf16 bits, round-to-nearest-even
__device__ __forceinline__ short f2bf(float f) {
    union { float f; uint32_t u; } v; v.f = f;
    uint32_t r = (v.u + 0x7FFFu + ((v.u >> 16) & 1u)) >> 16;
    return (short)r;
}
__device__ __forceinline__ float bf2f(uint32_t bits16) {
    union { uint32_t u; float f; } v; v.u = bits16 << 16;
    return v.f;
}

__device__ __forceinline__ int edge_at(const void* ei, int64_t idx, uint32_t is64) {
    if (is64) return (int)((const long long*)ei)[idx];
    return ((const int*)ei)[idx];
}

// ---- K0: zero bucket_woff + detect edge dtype (int64 vs int32) ---------
__global__ void k_init(const uint32_t* __restrict__ e_u32, uint32_t* __restrict__ flag,
                       uint32_t* __restrict__ bucket_woff) {
    const int t = threadIdx.x;
    if (t < NBUK) bucket_woff[t] = 0u;
    if (t == 0) {
        uint32_t o = 0;
        #pragma unroll
        for (int i = 1; i < 32; i += 2) o |= e_u32[i];
        flag[0] = (o == 0u) ? 1u : 0u; // 1 => int64
    }
}

// ---- K1: heterogeneous blocks: [0,nchunks) = edge binning,  ------------
// ----     [nchunks, nchunks+GEMM_BLOCKS) = x@W MFMA (no dinv) -----------
__global__ __launch_bounds__(512) void k_fused(const void* __restrict__ ei, int E, int nchunks,
                                               const uint32_t* __restrict__ flag,
                                               uint32_t* __restrict__ bucket_woff,
                                               uint32_t* __restrict__ gpairs,
                                               const float* __restrict__ x,
                                               const float* __restrict__ W,
                                               float* __restrict__ hs) {
    __shared__ uint32_t h[512];        // histogram -> inclusive scan in place
    __shared__ uint32_t ex[512];       // exclusive scan (frozen)
    __shared__ uint32_t pcnt[512];     // placement cursors
    __shared__ uint32_t gbase[512];    // global reservation per bucket
    __shared__ uint32_t sorted[CHUNK]; // bucket-sorted packed pairs (32 KB)
    __shared__ uint16_t sbuck[CHUNK];  // bucket id per slot (16 KB)

    const int t = threadIdx.x;

    if ((int)blockIdx.x < nchunks) {
        // ---------------- binA branch ----------------
        const uint32_t is64 = flag[0];
        const int base = blockIdx.x * CHUNK;
        const int chunk_n = min(CHUNK, E - base);

        h[t] = 0;
        __syncthreads();

        uint32_t pr[16];
        uint16_t bk[16];
        #pragma unroll
        for (int k = 0; k < 16; ++k) {
            int e = base + k * 512 + t;
            bk[k] = 0xFFFFu;
            if (e < E) {
                uint32_t s = (uint32_t)edge_at(ei, e, is64);
                uint32_t d = (uint32_t)edge_at(ei, (int64_t)E + e, is64);
                uint32_t b = d >> BSH;
                pr[k] = (s << BSH) | (d & ((1u << BSH) - 1u));
                bk[k] = (uint16_t)b;
                atomicAdd(&h[b], 1u);
            }
        }
        __syncthreads();

        const uint32_t hv = h[t];
        for (int off = 1; off < 512; off <<= 1) {
            uint32_t v = (t >= off) ? h[t - off] : 0u;
            __syncthreads();
            h[t] += v;
            __syncthreads();
        }
        ex[t] = h[t] - hv;
        pcnt[t] = ex[t];
        if (t < NBUK) gbase[t] = atomicAdd(&bucket_woff[t], hv);
        __syncthreads();

        #pragma unroll
        for (int k = 0; k < 16; ++k) {
            if (bk[k] != 0xFFFFu) {
                uint32_t slot = atomicAdd(&pcnt[bk[k]], 1u);
                sorted[slot] = pr[k];
                sbuck[slot] = bk[k];
            }
        }
        __syncthreads();

        #pragma unroll
        for (int k = 0; k < 16; ++k) {
            int i = k * 512 + t;
            if (i < chunk_n) {
                uint32_t b = sbuck[i];
                uint32_t pos = gbase[b] + ((uint32_t)i - ex[b]);
                gpairs[(size_t)b * CAP + pos] = sorted[i];
            }
        }
    } else {
        // ---------------- GEMM branch (no dinv) ----------------
        const int lane = t & 63;
        const int wid  = t >> 6; // 0..7
        const int tile = ((int)blockIdx.x - nchunks) * 8 + wid;
        if (tile * 16 >= N_NODES) return;
        const int c    = lane & 15;
        const int half = lane >> 4;

        bf16x8 bfrag[16];
        #pragma unroll
        for (int s = 0; s < 16; ++s) {
            #pragma unroll
            for (int e = 0; e < 8; ++e) {
                int k = 32 * s + 8 * half + e;
                bfrag[s][e] = f2bf(W[k * HOUT + c]);
            }
        }

        const int row = tile * 16 + c;
        const float* xr = x + (int64_t)row * F_IN;
        f32x4 acc = {0.f, 0.f, 0.f, 0.f};
        #pragma unroll
        for (int s = 0; s < 16; ++s) {
            const float4 a0 = *(const float4*)(xr + 32 * s + 8 * half);
            const float4 a1 = *(const float4*)(xr + 32 * s + 8 * half + 4);
            bf16x8 af;
            af[0] = f2bf(a0.x); af[1] = f2bf(a0.y); af[2] = f2bf(a0.z); af[3] = f2bf(a0.w);
            af[4] = f2bf(a1.x); af[5] = f2bf(a1.y); af[6] = f2bf(a1.z); af[7] = f2bf(a1.w);
            acc = __builtin_amdgcn_mfma_f32_16x16x32_bf16(af, bfrag[s], acc, 0, 0, 0);
        }

        #pragma unroll
        for (int r = 0; r < 4; ++r) {
            int orow = tile * 16 + 4 * half + r;
            hs[(int64_t)orow * HOUT + c] = acc[r];
        }
    }
}

// ---- K2: per-bucket histogram -> cnt; scale hs f32 -> hsb bf16 ----------
__global__ __launch_bounds__(256) void k_histscale(const uint32_t* __restrict__ bucket_woff,
                                                   const uint32_t* __restrict__ gpairs,
                                                   const float* __restrict__ hs,
                                                   uint32_t* __restrict__ cnt,
                                                   ushort* __restrict__ hsb) {
    const int b = blockIdx.x;
    const int t = threadIdx.x;
    const uint32_t count = bucket_woff[b];
    const uint32_t* gp = gpairs + (size_t)b * CAP;

    __shared__ uint32_t lc[256];
    lc[t] = 0;
    __syncthreads();
    for (uint32_t i = t; i < count; i += 256)
        atomicAdd(&lc[gp[i] & 255u], 1u);
    __syncthreads();

    const int gn = (b << BSH) + t;
    if (gn < N_NODES) {
        const uint32_t deg = lc[t];
        cnt[gn] = deg;
        const float dinv = rsqrtf((float)(deg + 1u));
        const float4* hr = (const float4*)(hs + (size_t)gn * HOUT);
        ushort o[16];
        #pragma unroll
        for (int q = 0; q < 4; ++q) {
            float4 v = hr[q];
            o[4*q + 0] = (ushort)f2bf(v.x * dinv);
            o[4*q + 1] = (ushort)f2bf(v.y * dinv);
            o[4*q + 2] = (ushort)f2bf(v.z * dinv);
            o[4*q + 3] = (ushort)f2bf(v.w * dinv);
        }
        ulonglong4* ow = (ulonglong4*)(hsb + (size_t)gn * HOUT);
        *ow = *(const ulonglong4*)o;
    }
}

// ---- K3: fused per-bucket sort(to LDS) + gather-aggregate + epilogue ----
__global__ __launch_bounds__(512) void k_sortagg(const uint32_t* __restrict__ bucket_woff,
                                                 const uint32_t* __restrict__ gpairs,
                                                 const uint32_t* __restrict__ cnt,
                                                 const ushort* __restrict__ hsb,
                                                 const float* __restrict__ bias,
                                                 float* __restrict__ out) {
    const int bk = blockIdx.x;
    const int t = threadIdx.x;
    const uint32_t count = bucket_woff[bk];
    const uint32_t* gp = gpairs + (size_t)bk * CAP;

    __shared__ uint32_t lc[256];   // per-node degree
    __shared__ uint32_t st[256];   // run start (frozen)
    __shared__ uint32_t cur[256];  // placement cursor
    __shared__ uint32_t sc[256];   // scan scratch
    __shared__ uint32_t lsrc[CAP]; // srcs sorted by dst-local (36 KB)

    if (t < 256) {
        int gn = (bk << BSH) + t;
        lc[t] = (gn < N_NODES) ? cnt[gn] : 0u;
        sc[t] = lc[t];
    }
    __syncthreads();
    for (int off = 1; off < 256; off <<= 1) {
        uint32_t v = 0;
        if (t < 256 && t >= off) v = sc[t - off];
        __syncthreads();
        if (t < 256) sc[t] += v;
        __syncthreads();
    }
    if (t < 256) {
        st[t] = sc[t] - lc[t];
        cur[t] = st[t];
    }
    __syncthreads();

    for (uint32_t i = t; i < count; i += 512) {
        uint32_t p = gp[i];
        uint32_t pos = atomicAdd(&cur[p & 255u], 1u);
        lsrc[pos] = p >> BSH;
    }
    __syncthreads();

    const int f = t & 15;
    const int g = t >> 4; // 0..31
    const float bf = bias[f];

    #pragma unroll
    for (int i = 0; i < 8; ++i) {
        int dl = g + 32 * i;
        int gn = (bk << BSH) + dl;
        if (gn >= N_NODES) break;
        const uint32_t s0 = st[dl];
        const uint32_t n  = lc[dl];

        float acc = 0.f;
        uint32_t j = 0;
        for (; j + 4 <= n; j += 4) {
            uint32_t a = lsrc[s0 + j], b2 = lsrc[s0 + j + 1];
            uint32_t c2 = lsrc[s0 + j + 2], d2 = lsrc[s0 + j + 3];
            float v0 = bf2f(hsb[(size_t)a  * HOUT + f]);
            float v1 = bf2f(hsb[(size_t)b2 * HOUT + f]);
            float v2 = bf2f(hsb[(size_t)c2 * HOUT + f]);
            float v3 = bf2f(hsb[(size_t)d2 * HOUT + f]);
            acc += (v0 + v1) + (v2 + v3);
        }
        for (; j < n; ++j)
            acc += bf2f(hsb[(size_t)lsrc[s0 + j] * HOUT + f]);

        const float dinv = rsqrtf((float)(n + 1u));
        const float self = bf2f(hsb[(size_t)gn * HOUT + f]);
        float v = fmaxf(fmaf(dinv, acc + self, bf), 0.f);

        float m = v;
        #pragma unroll
        for (int d = 1; d < 16; d <<= 1) m = fmaxf(m, __shfl_xor(m, d));
        float ex = __expf(v - m);
        float sum = ex;
        #pragma unroll
        for (int d = 1; d < 16; d <<= 1) sum += __shfl_xor(sum, d);
        out[(size_t)gn * HOUT + f] = v - (m + __logf(sum));
    }
}

extern "C" void kernel_launch(void* const* d_in, const int* in_sizes, int n_in,
                              void* d_out, int out_size, void* d_ws, size_t ws_size,
                              hipStream_t stream) {
    const float* x  = (const float*)d_in[0];
    const void*  ei = d_in[1];
    const float* W  = (const float*)d_in[2];
    const float* b  = (const float*)d_in[3];
    float* out = (float*)d_out;
    const int E = in_sizes[1] / 2;
    const int nchunks = (E + CHUNK - 1) / CHUNK;

    char* ws = (char*)d_ws;
    uint32_t* flag        = (uint32_t*)ws;                  // 4 B
    uint32_t* bucket_woff = (uint32_t*)(ws + 1024);         // 1.6 KB
    uint32_t* gpairs      = (uint32_t*)(ws + (1 << 20));    // 14.42 MB
    ushort*   hsb         = (ushort*)(ws + (16 << 20));     // 3.2 MB
    uint32_t* cnt         = (uint32_t*)(ws + (20 << 20));   // 400 KB
    float*    hs          = (float*)(ws + (21 << 20));      // 6.4 MB

    k_init<<<1, 512, 0, stream>>>((const uint32_t*)ei, flag, bucket_woff);
    k_fused<<<nchunks + GEMM_BLOCKS, 512, 0, stream>>>(ei, E, nchunks, flag,
                                                       bucket_woff, gpairs, x, W, hs);
    k_histscale<<<NBUK, 256, 0, stream>>>(bucket_woff, gpairs, hs, cnt, hsb);
    k_sortagg<<<NBUK, 512, 0, stream>>>(bucket_woff, gpairs, cnt, hsb, b, out);
}

// Round 7
// 104.951 us; speedup vs baseline: 4.1883x; 1.0687x over previous
//
#include <hip/hip_runtime.h>
#include <hip/hip_bf16.h>
#include <stdint.h>

#define N_NODES 100000
#define F_IN    512
#define HOUT    16

#define BSH   8                       // 256 nodes per bucket
#define NBUK  391                     // ceil(100000 / 256)
#define CAP   9216                    // per-bucket capacity (mean 8184, +11 sigma)
#define CHUNK 8192                    // edges per binA block
#define GEMM_BLOCKS 782               // ceil(6250 tiles / 8 waves)

typedef __attribute__((ext_vector_type(8))) short bf16x8;
typedef __attribute__((ext_vector_type(4))) float f32x4;

// f32 -> bf16 bits, round-to-nearest-even
__device__ __forceinline__ short f2bf(float f) {
    union { float f; uint32_t u; } v; v.f = f;
    uint32_t r = (v.u + 0x7FFFu + ((v.u >> 16) & 1u)) >> 16;
    return (short)r;
}
__device__ __forceinline__ float bf2f(uint32_t bits16) {
    union { uint32_t u; float f; } v; v.u = bits16 << 16;
    return v.f;
}

__device__ __forceinline__ int edge_at(const void* ei, int64_t idx, uint32_t is64) {
    if (is64) return (int)((const long long*)ei)[idx];
    return ((const int*)ei)[idx];
}

// ---- K0: zero bucket_woff + detect edge dtype (int64 vs int32) ---------
__global__ void k_init(const uint32_t* __restrict__ e_u32, uint32_t* __restrict__ flag,
                       uint32_t* __restrict__ bucket_woff) {
    const int t = threadIdx.x;
    if (t < NBUK) bucket_woff[t] = 0u;
    if (t == 0) {
        uint32_t o = 0;
        #pragma unroll
        for (int i = 1; i < 32; i += 2) o |= e_u32[i];
        flag[0] = (o == 0u) ? 1u : 0u; // 1 => int64
    }
}

// ---- K1: heterogeneous blocks: [0,nchunks) = edge binning,  ------------
// ----     [nchunks, ...) = x@W MFMA -> unscaled bf16 hb -----------------
__global__ __launch_bounds__(512) void k_fused(const void* __restrict__ ei, int E, int nchunks,
                                               const uint32_t* __restrict__ flag,
                                               uint32_t* __restrict__ bucket_woff,
                                               uint32_t* __restrict__ gpairs,
                                               const float* __restrict__ x,
                                               const float* __restrict__ W,
                                               ushort* __restrict__ hb) {
    __shared__ uint32_t h[512];        // histogram -> inclusive scan in place
    __shared__ uint32_t ex[512];       // exclusive scan (frozen)
    __shared__ uint32_t pcnt[512];     // placement cursors
    __shared__ uint32_t gbase[512];    // global reservation per bucket
    __shared__ uint32_t sorted[CHUNK]; // bucket-sorted packed pairs (32 KB)
    __shared__ uint16_t sbuck[CHUNK];  // bucket id per slot (16 KB)

    const int t = threadIdx.x;

    if ((int)blockIdx.x < nchunks) {
        // ---------------- binA branch ----------------
        const uint32_t is64 = flag[0];
        const int base = blockIdx.x * CHUNK;
        const int chunk_n = min(CHUNK, E - base);

        h[t] = 0;
        __syncthreads();

        uint32_t pr[16];
        uint16_t bk[16];
        #pragma unroll
        for (int k = 0; k < 16; ++k) {
            int e = base + k * 512 + t;
            bk[k] = 0xFFFFu;
            if (e < E) {
                uint32_t s = (uint32_t)edge_at(ei, e, is64);
                uint32_t d = (uint32_t)edge_at(ei, (int64_t)E + e, is64);
                uint32_t b = d >> BSH;
                pr[k] = (s << BSH) | (d & ((1u << BSH) - 1u));
                bk[k] = (uint16_t)b;
                atomicAdd(&h[b], 1u);
            }
        }
        __syncthreads();

        const uint32_t hv = h[t];
        for (int off = 1; off < 512; off <<= 1) {
            uint32_t v = (t >= off) ? h[t - off] : 0u;
            __syncthreads();
            h[t] += v;
            __syncthreads();
        }
        ex[t] = h[t] - hv;
        pcnt[t] = ex[t];
        if (t < NBUK) gbase[t] = atomicAdd(&bucket_woff[t], hv);
        __syncthreads();

        #pragma unroll
        for (int k = 0; k < 16; ++k) {
            if (bk[k] != 0xFFFFu) {
                uint32_t slot = atomicAdd(&pcnt[bk[k]], 1u);
                sorted[slot] = pr[k];
                sbuck[slot] = bk[k];
            }
        }
        __syncthreads();

        #pragma unroll
        for (int k = 0; k < 16; ++k) {
            int i = k * 512 + t;
            if (i < chunk_n) {
                uint32_t b = sbuck[i];
                uint32_t pos = gbase[b] + ((uint32_t)i - ex[b]);
                gpairs[(size_t)b * CAP + pos] = sorted[i];
            }
        }
    } else {
        // ---------------- GEMM branch (unscaled bf16 out) ----------------
        const int lane = t & 63;
        const int wid  = t >> 6; // 0..7
        const int tile = ((int)blockIdx.x - nchunks) * 8 + wid;
        if (tile * 16 >= N_NODES) return;
        const int c    = lane & 15;
        const int half = lane >> 4;

        bf16x8 bfrag[16];
        #pragma unroll
        for (int s = 0; s < 16; ++s) {
            #pragma unroll
            for (int e = 0; e < 8; ++e) {
                int k = 32 * s + 8 * half + e;
                bfrag[s][e] = f2bf(W[k * HOUT + c]);
            }
        }

        const int row = tile * 16 + c;
        const float* xr = x + (int64_t)row * F_IN;
        f32x4 acc = {0.f, 0.f, 0.f, 0.f};
        #pragma unroll
        for (int s = 0; s < 16; ++s) {
            const float4 a0 = *(const float4*)(xr + 32 * s + 8 * half);
            const float4 a1 = *(const float4*)(xr + 32 * s + 8 * half + 4);
            bf16x8 af;
            af[0] = f2bf(a0.x); af[1] = f2bf(a0.y); af[2] = f2bf(a0.z); af[3] = f2bf(a0.w);
            af[4] = f2bf(a1.x); af[5] = f2bf(a1.y); af[6] = f2bf(a1.z); af[7] = f2bf(a1.w);
            acc = __builtin_amdgcn_mfma_f32_16x16x32_bf16(af, bfrag[s], acc, 0, 0, 0);
        }

        #pragma unroll
        for (int r = 0; r < 4; ++r) {
            int orow = tile * 16 + 4 * half + r;
            hb[(int64_t)orow * HOUT + c] = (ushort)f2bf(acc[r]);
        }
    }
}

// ---- K2: per-bucket histogram -> cnt; scale hb *= dinv in place --------
__global__ __launch_bounds__(256) void k_hist(const uint32_t* __restrict__ bucket_woff,
                                              const uint32_t* __restrict__ gpairs,
                                              uint32_t* __restrict__ cnt,
                                              ushort* __restrict__ hb) {
    const int b = blockIdx.x;
    const int t = threadIdx.x;
    const uint32_t count = bucket_woff[b];
    const uint32_t* gp = gpairs + (size_t)b * CAP;

    __shared__ uint32_t lc[256];
    lc[t] = 0;
    __syncthreads();
    for (uint32_t i = t; i < count; i += 256)
        atomicAdd(&lc[gp[i] & 255u], 1u);
    __syncthreads();

    const int gn = (b << BSH) + t;
    if (gn < N_NODES) {
        const uint32_t deg = lc[t];
        cnt[gn] = deg;
        const float dinv = rsqrtf((float)(deg + 1u));
        ushort* row = hb + (size_t)gn * HOUT;
        ulonglong4 rv = *(const ulonglong4*)row;
        ushort u[16];
        *(ulonglong4*)u = rv;
        #pragma unroll
        for (int q = 0; q < 16; ++q)
            u[q] = (ushort)f2bf(bf2f(u[q]) * dinv);
        *(ulonglong4*)row = *(const ulonglong4*)u;
    }
}

// ---- K3: fused per-bucket sort(to LDS) + gather-aggregate + epilogue ----
// 1024 threads: 16 waves/block so doubled-up CUs stay co-resident.
__global__ __launch_bounds__(1024) void k_sortagg(const uint32_t* __restrict__ bucket_woff,
                                                  const uint32_t* __restrict__ gpairs,
                                                  const uint32_t* __restrict__ cnt,
                                                  const ushort* __restrict__ hb,
                                                  const float* __restrict__ bias,
                                                  float* __restrict__ out) {
    const int bk = blockIdx.x;
    const int t = threadIdx.x;
    const uint32_t count = bucket_woff[bk];
    const uint32_t* gp = gpairs + (size_t)bk * CAP;

    __shared__ uint32_t lc[256];   // per-node degree
    __shared__ uint32_t st[256];   // run start (frozen)
    __shared__ uint32_t cur[256];  // placement cursor
    __shared__ uint32_t sc[256];   // scan scratch
    __shared__ uint32_t lsrc[CAP]; // srcs sorted by dst-local (36 KB)

    if (t < 256) {
        int gn = (bk << BSH) + t;
        lc[t] = (gn < N_NODES) ? cnt[gn] : 0u;
        sc[t] = lc[t];
    }
    __syncthreads();
    for (int off = 1; off < 256; off <<= 1) {
        uint32_t v = 0;
        if (t < 256 && t >= off) v = sc[t - off];
        __syncthreads();
        if (t < 256) sc[t] += v;
        __syncthreads();
    }
    if (t < 256) {
        st[t] = sc[t] - lc[t];
        cur[t] = st[t];
    }
    __syncthreads();

    for (uint32_t i = t; i < count; i += 1024) {
        uint32_t p = gp[i];
        uint32_t pos = atomicAdd(&cur[p & 255u], 1u);
        lsrc[pos] = p >> BSH;
    }
    __syncthreads();

    const int f = t & 15;
    const int g = t >> 4; // 0..63
    const float bf = bias[f];

    #pragma unroll
    for (int i = 0; i < 4; ++i) {
        int dl = g + 64 * i;
        int gn = (bk << BSH) + dl;
        if (gn >= N_NODES) break;
        const uint32_t s0 = st[dl];
        const uint32_t n  = lc[dl];

        float acc = 0.f;
        uint32_t j = 0;
        for (; j + 4 <= n; j += 4) {
            uint32_t a = lsrc[s0 + j], b2 = lsrc[s0 + j + 1];
            uint32_t c2 = lsrc[s0 + j + 2], d2 = lsrc[s0 + j + 3];
            float v0 = bf2f(hb[(size_t)a  * HOUT + f]);
            float v1 = bf2f(hb[(size_t)b2 * HOUT + f]);
            float v2 = bf2f(hb[(size_t)c2 * HOUT + f]);
            float v3 = bf2f(hb[(size_t)d2 * HOUT + f]);
            acc += (v0 + v1) + (v2 + v3);
        }
        for (; j < n; ++j)
            acc += bf2f(hb[(size_t)lsrc[s0 + j] * HOUT + f]);

        const float dinv = rsqrtf((float)(n + 1u));
        const float self = bf2f(hb[(size_t)gn * HOUT + f]);
        float v = fmaxf(fmaf(dinv, acc + self, bf), 0.f);

        float m = v;
        #pragma unroll
        for (int d = 1; d < 16; d <<= 1) m = fmaxf(m, __shfl_xor(m, d));
        float ex = __expf(v - m);
        float sum = ex;
        #pragma unroll
        for (int d = 1; d < 16; d <<= 1) sum += __shfl_xor(sum, d);
        out[(size_t)gn * HOUT + f] = v - (m + __logf(sum));
    }
}

extern "C" void kernel_launch(void* const* d_in, const int* in_sizes, int n_in,
                              void* d_out, int out_size, void* d_ws, size_t ws_size,
                              hipStream_t stream) {
    const float* x  = (const float*)d_in[0];
    const void*  ei = d_in[1];
    const float* W  = (const float*)d_in[2];
    const float* b  = (const float*)d_in[3];
    float* out = (float*)d_out;
    const int E = in_sizes[1] / 2;
    const int nchunks = (E + CHUNK - 1) / CHUNK;

    char* ws = (char*)d_ws;
    uint32_t* flag        = (uint32_t*)ws;                  // 4 B
    uint32_t* bucket_woff = (uint32_t*)(ws + 1024);         // 1.6 KB
    uint32_t* gpairs      = (uint32_t*)(ws + (1 << 20));    // 14.42 MB
    ushort*   hb          = (ushort*)(ws + (16 << 20));     // 3.2 MB
    uint32_t* cnt         = (uint32_t*)(ws + (20 << 20));   // 400 KB

    k_init<<<1, 512, 0, stream>>>((const uint32_t*)ei, flag, bucket_woff);
    k_fused<<<nchunks + GEMM_BLOCKS, 512, 0, stream>>>(ei, E, nchunks, flag,
                                                       bucket_woff, gpairs, x, W, hb);
    k_hist<<<NBUK, 256, 0, stream>>>(bucket_woff, gpairs, cnt, hb);
    k_sortagg<<<NBUK, 1024, 0, stream>>>(bucket_woff, gpairs, cnt, hb, b, out);
}